// Round 1
// baseline (75.651 us; speedup 1.0000x reference)
//
#include <hip/hip_runtime.h>
#include <hip/hip_bf16.h>

// FConv2d exact reduced form:
// out[b, d*16+n, r, s] =
//   0.5 * sum_{c2<32,u,v<3} W[n,c2,2-u,2-v] * (xa + xb)[r+u, s+v]
// xa = x[b,(8d-c2)%128], xb = x[b,(-8d-c2)%128], zero outside 32x32;
// xcomb[16-d] == xcomb[d]  =>  compute d=0..8, mirror-write 9..15.
// (Verified lineage: r3 fp32 7.8e-3, r4..r10 bf16-MFMA 1.56e-2 vs np ref.)
//
// Round 11: (a) weight fragments precomputed ONCE by a prep kernel into
// d_ws in the exact af[t][lane] layout -> main kernel loads them as 9
// coalesced 1KB dwordx4 from L2, removing per-block 18.4KB uncoalesced
// weight reads + 4608 cvt + 4608 ds_write_b16 and 11.5KB LDS;
// (b) register-lean staging (j processed in quads, h2 accumulators) to
// stay under the __launch_bounds__(256,6) VGPR cap without spills.

typedef __attribute__((ext_vector_type(8))) short short8;
typedef __attribute__((ext_vector_type(4))) float floatx4;

#define NT 256
#define SROW 35              // xs row stride in 16-B granules
#define SOCT (6 * SROW)      // granules per c2-octet (6 staged rows)

// ---- one-time weight fragment prep: wfg[(t*64+lane)*8+j] =
//      bf16( W[n=lane&15][c2=(lane>>4)*8+j][k=8-t] ) ----
__global__ __launch_bounds__(576, 1)
void prep_weights(const float* __restrict__ wgt, short* __restrict__ wfg) {
    const int tid  = threadIdx.x;     // 0..575
    const int t    = tid >> 6;        // 0..8
    const int lane = tid & 63;
    const int n    = lane & 15;
    const int q    = lane >> 4;
    const int k    = 8 - t;
    short8 v;
#pragma unroll
    for (int j = 0; j < 8; ++j) {
        const int c2 = q * 8 + j;
        __hip_bfloat16 h = __float2bfloat16(wgt[(n * 32 + c2) * 9 + k]);
        v[j] = __builtin_bit_cast(short, h);
    }
    *(short8*)&wfg[tid * 8] = v;
}

__global__ __launch_bounds__(NT, 6)
void fconv_mfma(const float* __restrict__ x,
                const short* __restrict__ wfg,
                float* __restrict__ out) {
    __shared__ __align__(16) short xs[4 * SOCT * 8];   // 13440 B (only LDS now)

    const int band = blockIdx.x;      // 0..7 : 4-row band
    const int d    = blockIdx.y;      // 0..8
    const int b    = blockIdx.z;      // 0..15
    const int r0   = band * 4;
    const int tid  = threadIdx.x;
    const int dup  = ((d & 7) == 0);  // d==0 or d==8: xa == xb
    const int lane = tid & 63;

    const float* xb_base = x + ((size_t)b << 17);   // b*128*1024

    // ---- stage xcomb: 192 tasks (oct, sq, r), 4 granules each ----
    if (tid < 192) {
        const int oct = tid / 48;         // 0..3
        const int rem = tid - oct * 48;   // 0..47
        const int sq  = rem / 6;          // 0..7
        const int r   = rem - sq * 6;     // 0..5  (fastest -> <=2-way writes)
        const int gr  = r0 + r;
        union { __hip_bfloat162 h2[4]; short8 s8; } u[4];
        if (gr < 32) {
            const float* base = xb_base + (gr << 5) + (sq << 2);
#pragma unroll
            for (int half = 0; half < 2; ++half) {   // j = half*4 .. half*4+3
                float va[4][4];
#pragma unroll
                for (int jj = 0; jj < 4; ++jj) {
                    const int c2  = oct * 8 + half * 4 + jj;
                    const int c1a = (8 * d - c2) & 127;
                    float4 A = *(const float4*)(base + (c1a << 10));
                    if (!dup) {
                        const int c1b = (-8 * d - c2) & 127;
                        const float4 Bv = *(const float4*)(base + (c1b << 10));
                        A.x = 0.5f * (A.x + Bv.x); A.y = 0.5f * (A.y + Bv.y);
                        A.z = 0.5f * (A.z + Bv.z); A.w = 0.5f * (A.w + Bv.w);
                    }
                    va[jj][0] = A.x; va[jj][1] = A.y;
                    va[jj][2] = A.z; va[jj][3] = A.w;
                }
#pragma unroll
                for (int ss = 0; ss < 4; ++ss)
#pragma unroll
                    for (int p = 0; p < 2; ++p)
                        u[ss].h2[half * 2 + p] = __float22bfloat162_rn(
                            make_float2(va[2 * p][ss], va[2 * p + 1][ss]));
            }
        } else {
#pragma unroll
            for (int ss = 0; ss < 4; ++ss)
#pragma unroll
                for (int j = 0; j < 8; ++j) u[ss].s8[j] = 0;
        }
#pragma unroll
        for (int ss = 0; ss < 4; ++ss)
            *(short8*)&xs[(oct * SOCT + r * SROW + (sq << 2) + ss) << 3] = u[ss].s8;
    }
    // s-apron (s = 32, 33) zeros: 4 oct * 6 r * 2 s = 48 granules
    if (tid < 48) {
        const int oct = tid / 12;
        const int rem = tid - oct * 12;
        const int r   = rem >> 1;
        const int s   = 32 + (rem & 1);
        short8 z = {0, 0, 0, 0, 0, 0, 0, 0};
        *(short8*)&xs[(oct * SOCT + r * SROW + s) << 3] = z;
    }

    // ---- A fragments: 9 coalesced dwordx4 from the 9.2KB L2-resident
    //      precomputed buffer (issued before the barrier; latency hides
    //      under other waves' staging) ----
    short8 af[9];
    const short8* wf8 = (const short8*)wfg;
#pragma unroll
    for (int t = 0; t < 9; ++t)
        af[t] = wf8[t * 64 + lane];

    __syncthreads();

    // ---- compute: wave w -> output row r0+w, 2 col-half tiles ----
    const int c = lane & 15;     // A: n index; B/D: col (s offset)
    const int q = lane >> 4;     // k-octet; D: row group (n = q*4+reg)
    const int w = tid >> 6;
#pragma unroll
    for (int i = 0; i < 2; ++i) {
        const int s0 = i << 4;            // 0 or 16
        floatx4 acc = {0.f, 0.f, 0.f, 0.f};
        const short* basep = &xs[(q * SOCT + w * SROW + s0 + c) << 3];
#pragma unroll
        for (int u = 0; u < 3; ++u)
#pragma unroll
            for (int v = 0; v < 3; ++v) {
                const short8 bf = *(const short8*)(basep + ((u * SROW + v) << 3));
                acc = __builtin_amdgcn_mfma_f32_16x16x32_bf16(af[u * 3 + v], bf, acc, 0, 0, 0);
            }
        // D: col = c (s = s0+c), row = q*4+reg (n)
        float* op = out + (size_t)(((b * 256 + d * 16 + q * 4) * 32 + (r0 + w)) * 32 + s0 + c);
        op[0]    = acc.x;
        op[1024] = acc.y;
        op[2048] = acc.z;
        op[3072] = acc.w;
        if (d >= 1 && d <= 7) {   // mirror channel group (16-d)
            float* op2 = op + (size_t)(16 - 2 * d) * 16384;  // ((16-d)-d)*16*1024
            op2[0]    = acc.x;
            op2[1024] = acc.y;
            op2[2048] = acc.z;
            op2[3072] = acc.w;
        }
    }
}

extern "C" void kernel_launch(void* const* d_in, const int* in_sizes, int n_in,
                              void* d_out, int out_size, void* d_ws, size_t ws_size,
                              hipStream_t stream) {
    const float* x   = (const float*)d_in[0];   // (16,128,32,32) fp32
    const float* wgt = (const float*)d_in[1];   // (16,32,3,3)   fp32
    float* out = (float*)d_out;                 // (16,256,32,32) fp32
    short* wfg = (short*)d_ws;                  // 9216 B of workspace
    (void)in_sizes; (void)n_in; (void)out_size; (void)ws_size;

    prep_weights<<<dim3(1), dim3(576), 0, stream>>>(wgt, wfg);

    dim3 grid(8, 9, 16);    // (4-row band, d=0..8, b)
    fconv_mfma<<<grid, dim3(NT), 0, stream>>>(x, wfg, out);
}

// Round 2
// 74.540 us; speedup vs baseline: 1.0149x; 1.0149x over previous
//
#include <hip/hip_runtime.h>
#include <hip/hip_bf16.h>

// FConv2d, round 12 restructure: one block = (b, output-row-pair), ALL d=0..8.
// out[b, d*16+n, r, s] = sum_{c2,u,v} 0.5*W[n,c2,2-u,2-v] *
//                        ( x[b,(8d-c2)%128] + x[b,(-8d-c2)%128] )[r+u, s+v]
// Stage RAW x (not per-d xcomb) in LDS channel-fastest with an UNWRAPPED,
// duplicated channel axis: slot L = m + 95 for m in [-95, 64], value x[m mod 128].
// Then every (d, branch, q) B-fragment is a contiguous 16B ds_read at
// L0 = 8*(11+d-q) (xa) / 8*(11-d-q) (xb) -- always 16B-aligned.
// A-fragment element (q,j) = 0.5*W[n][8q+7-j][8-t] (j-reversed octets) pairs with
// ascending-channel B. d=0/8: xa==xb windows -> 2*(0.5W*xa) = W*xa, correct.
// Mirror d'=16-d written from same acc (d=1..7).
// x read once per block: 16.8 MB total vs 50 MB before (L3 is poison-flushed
// every iteration by the harness's 256MiB ws fill -> cold-cache traffic is
// what the old kernel was paying for).

typedef __attribute__((ext_vector_type(8))) short short8;
typedef __attribute__((ext_vector_type(4))) float floatx4;

#define NT 256
#define LCH 168                 // padded channel-slot dim (160 used; pad kills bank conflicts)
#define SROWS 34                // s entries per row (cols 0..33, 32..33 zero)
#define XSROW (SROWS * LCH)     // shorts per staged row

__global__ __launch_bounds__(NT, 2)
void fconv_mfma(const float* __restrict__ x,
                const float* __restrict__ wgt,
                float* __restrict__ out) {
    __shared__ __align__(16) short xs[4 * XSROW];   // 45,696 B

    const int rq  = blockIdx.x;   // 0..15 : output row-pair
    const int b   = blockIdx.y;   // 0..15
    const int r0  = rq * 2;
    const int tid = threadIdx.x;
    const int lane = tid & 63;
    const int wv  = tid >> 6;

    const int n = lane & 15;      // A row (filter n) / D col lane
    const int q = lane >> 4;      // k-octet

    // ---- A fragments in-register: af[t][j] = bf16(0.5*W[n][8q+7-j][8-t]) ----
    // 18 coalesced float4 loads of the contiguous 72-float strip W[n][8q..8q+7][*]
    float wreg[72];
    {
        const float4* wp = (const float4*)(wgt + (n * 288 + q * 72));
#pragma unroll
        for (int i = 0; i < 18; ++i) {
            const float4 t4 = wp[i];
            wreg[4 * i]     = t4.x; wreg[4 * i + 1] = t4.y;
            wreg[4 * i + 2] = t4.z; wreg[4 * i + 3] = t4.w;
        }
    }
    short8 af[9];
#pragma unroll
    for (int t = 0; t < 9; ++t)
#pragma unroll
        for (int j = 0; j < 8; ++j) {
            const int f = (7 - j) * 9 + (8 - t);       // (c2-within-octet)*9 + tap
            __hip_bfloat16 hh = __float2bfloat16(0.5f * wreg[f]);
            af[t][j] = __builtin_bit_cast(short, hh);
        }

    // ---- stage raw x rows r0..r0+3 -> xs[lrow][col][L], L = ch+95 and/or ch-33 ----
    const int ch = tid & 127;
    const int h  = tid >> 7;
    const bool w1 = (ch <= 64);    // slot L = ch + 95  (m = ch)
    const bool w2 = (ch >= 33);    // slot L = ch - 33  (m = ch - 128)
#pragma unroll
    for (int rr = 0; rr < 2; ++rr) {
        const int lrow = 2 * h + rr;
        const int grow = r0 + lrow;
        short* rowbase = &xs[lrow * XSROW];
        if (grow < 32) {
            const float* rowp = x + ((size_t)((b * 128 + ch) * 32 + grow) << 5);
#pragma unroll
            for (int cq = 0; cq < 8; ++cq) {
                const float4 v4 = *(const float4*)(rowp + cq * 4);
                const float vv[4] = {v4.x, v4.y, v4.z, v4.w};
#pragma unroll
                for (int e = 0; e < 4; ++e) {
                    const int col = cq * 4 + e;
                    __hip_bfloat16 hb = __float2bfloat16(vv[e]);
                    const short hv = __builtin_bit_cast(short, hb);
                    if (w1) rowbase[col * LCH + ch + 95] = hv;   // 2B-contig across lanes: conflict-free
                    if (w2) rowbase[col * LCH + ch - 33] = hv;
                }
            }
        } else {   // rows 32,33 (only rq==15): zero
#pragma unroll
            for (int col = 0; col < 32; ++col) {
                if (w1) rowbase[col * LCH + ch + 95] = 0;
                if (w2) rowbase[col * LCH + ch - 33] = 0;
            }
        }
    }
    // zero the s=32,33 apron strips for all 4 rows (contiguous 336 shorts/row)
    if (tid < 168) {
        const int row = tid / 42;
        const int g   = tid - row * 42;
        short8 z = {0, 0, 0, 0, 0, 0, 0, 0};
        *(short8*)&xs[(row * SROWS + 32) * LCH + g * 8] = z;
    }

    __syncthreads();

    // ---- compute: wave wv -> (output row lr, col-half sh); loop d=0..8 ----
    const int lr = wv >> 1;
    const int sh = wv & 1;
    const int s0 = sh << 4;
    const int bpi = (lr * SROWS + s0 + n) * LCH - 8 * q;   // lane base (index form)

    for (int d = 0; d <= 8; ++d) {
        floatx4 a0 = {0.f, 0.f, 0.f, 0.f}, a1 = {0.f, 0.f, 0.f, 0.f};
        floatx4 b0 = {0.f, 0.f, 0.f, 0.f}, b1 = {0.f, 0.f, 0.f, 0.f};
#pragma unroll
        for (int u = 0; u < 3; ++u)
#pragma unroll
            for (int v = 0; v < 3; ++v) {
                const int t = u * 3 + v;
                const int si = bpi + (u * SROWS + v) * LCH;
                const short8 ba = *(const short8*)&xs[si + 8 * (11 + d)];  // xa window
                const short8 bb = *(const short8*)&xs[si + 8 * (11 - d)];  // xb window
                if (t & 1) {   // 4 interleaved acc chains: dep distance 4 MFMAs
                    a1 = __builtin_amdgcn_mfma_f32_16x16x32_bf16(af[t], ba, a1, 0, 0, 0);
                    b1 = __builtin_amdgcn_mfma_f32_16x16x32_bf16(af[t], bb, b1, 0, 0, 0);
                } else {
                    a0 = __builtin_amdgcn_mfma_f32_16x16x32_bf16(af[t], ba, a0, 0, 0, 0);
                    b0 = __builtin_amdgcn_mfma_f32_16x16x32_bf16(af[t], bb, b0, 0, 0, 0);
                }
            }
        const floatx4 acc = (a0 + a1) + (b0 + b1);
        // D layout: col = n-lane (s), row = q*4 + reg (filter n)
        float* op = out + ((size_t)((b * 256 + d * 16 + q * 4) * 32 + (r0 + lr)) << 5) + s0 + n;
        op[0]    = acc.x;
        op[1024] = acc.y;
        op[2048] = acc.z;
        op[3072] = acc.w;
        if (d >= 1 && d <= 7) {   // mirror channel group 16-d
            float* op2 = op + (size_t)(16 - 2 * d) * 16384;
            op2[0]    = acc.x;
            op2[1024] = acc.y;
            op2[2048] = acc.z;
            op2[3072] = acc.w;
        }
    }
}

extern "C" void kernel_launch(void* const* d_in, const int* in_sizes, int n_in,
                              void* d_out, int out_size, void* d_ws, size_t ws_size,
                              hipStream_t stream) {
    const float* x   = (const float*)d_in[0];   // (16,128,32,32) fp32
    const float* wgt = (const float*)d_in[1];   // (16,32,3,3)   fp32
    float* out = (float*)d_out;                 // (16,256,32,32) fp32
    (void)in_sizes; (void)n_in; (void)out_size; (void)d_ws; (void)ws_size;

    fconv_mfma<<<dim3(16, 16), dim3(NT), 0, stream>>>(x, wgt, out);
}

// Round 6
// 70.472 us; speedup vs baseline: 1.0735x; 1.0577x over previous
//
#include <hip/hip_runtime.h>
#include <hip/hip_bf16.h>

// FConv2d, round 13 (3rd resubmit; r3/r4/r5 acquisition timeouts — no data):
// round-12 dataflow (one block = (b, row-pair), all d; raw-x LDS with
// unwrapped duplicated channel axis), execution restructured:
//  - NT=512: waves 0-3 compute even d {0,2,4,6,8} (d=0/8 halved: windows
//    identical -> 9 MFMA, acc doubled), waves 4-7 odd d {1,3,5,7}.
//    72 MFMA/wave balanced; 2 waves/SIMD (was 1).
//  - staging vectorized: granule tasks -> 8 coalesced global_load_dword +
//    4 packed cvt + 1 ds_write_b128 (was 128 scalar ds_write_b16/thread).
//  - weights staged in LDS (flip + 0.5 folded into write), af = 9 ds_read_b128.
//  - compute_d<D> template: all LDS offsets compile-time immediates.
// Identity: out[b,d*16+n,r,s] = sum 0.5W[n,c2,2-u,2-v]*(xa+xb)[r+u,s+v],
// xa=x[(8d-c2)%128], xb=x[(-8d-c2)%128]; mirror d'=16-d same acc.
// Fragment pairing (r12-verified): af[t][j]=0.5W[n][8q+7-j][8-t] with
// B-window L0 = 8*(11 +/- d - q).

typedef __attribute__((ext_vector_type(8))) short short8;
typedef __attribute__((ext_vector_type(4))) float floatx4;

#define NT 512
#define LCH 168                 // padded channel-slot dim (160 used)
#define SROWS 34                // cols per staged row (32..33 zero apron)
#define XSROW (SROWS * LCH)

template<int D, bool DUP>
__device__ __forceinline__ void compute_d(const char* basep, const short8 af[9],
                                          float* opbase) {
    floatx4 a0 = {0.f,0.f,0.f,0.f}, a1 = {0.f,0.f,0.f,0.f};
    floatx4 b0 = {0.f,0.f,0.f,0.f}, b1 = {0.f,0.f,0.f,0.f};
#pragma unroll
    for (int u = 0; u < 3; ++u)
#pragma unroll
        for (int v = 0; v < 3; ++v) {
            const int t = u * 3 + v;
            const short8 ba = *(const short8*)(basep +
                ((u * SROWS + v) * LCH + 8 * (8 + D)) * 2);
            if (t & 1) a1 = __builtin_amdgcn_mfma_f32_16x16x32_bf16(af[t], ba, a1, 0, 0, 0);
            else       a0 = __builtin_amdgcn_mfma_f32_16x16x32_bf16(af[t], ba, a0, 0, 0, 0);
            if (!DUP) {
                const short8 bb = *(const short8*)(basep +
                    ((u * SROWS + v) * LCH + 8 * (8 - D)) * 2);
                if (t & 1) b1 = __builtin_amdgcn_mfma_f32_16x16x32_bf16(af[t], bb, b1, 0, 0, 0);
                else       b0 = __builtin_amdgcn_mfma_f32_16x16x32_bf16(af[t], bb, b0, 0, 0, 0);
            }
        }
    floatx4 acc = a0 + a1;
    if (DUP) acc = acc + acc;          // xa==xb: 2*(0.5W*xa) = W*xa, bit-identical
    else     acc = acc + (b0 + b1);
    float* op = opbase + D * 16384;    // D*16*1024 floats
    op[0]    = acc.x;
    op[1024] = acc.y;
    op[2048] = acc.z;
    op[3072] = acc.w;
    if (D >= 1 && D <= 7) {            // mirror channel group 16-D
        float* op2 = opbase + (16 - D) * 16384;
        op2[0]    = acc.x;
        op2[1024] = acc.y;
        op2[2048] = acc.z;
        op2[3072] = acc.w;
    }
}

__global__ __launch_bounds__(NT, 2)
void fconv_mfma(const float* __restrict__ x,
                const float* __restrict__ wgt,
                float* __restrict__ out) {
    __shared__ __align__(16) short xs[4 * XSROW];   // 45,696 B
    __shared__ __align__(16) short wf[9 * 640];     // 11,520 B

    const int rq   = blockIdx.x;   // 0..15 : output row-pair
    const int b    = blockIdx.y;   // 0..15
    const int r0   = rq * 2;
    const int tid  = threadIdx.x;
    const int lane = tid & 63;
    const int wv   = tid >> 6;

    // ---- weights -> LDS: wf[(8-k)*640 + n*40 + oct*8 + (7-j)] = 0.5*W[n][8oct+j][k]
    {
        const int n  = tid >> 5;        // 0..15
        const int c2 = tid & 31;
        const float* wb = wgt + (size_t)(n * 32 + c2) * 9;
        const int pos = n * 40 + (c2 & 24) + (7 - (c2 & 7));
#pragma unroll
        for (int k = 0; k < 9; ++k) {
            __hip_bfloat16 h = __float2bfloat16(0.5f * wb[k]);
            wf[(8 - k) * 640 + pos] = __builtin_bit_cast(short, h);
        }
    }

    // ---- stage raw x: 2560 granule tasks (lrow, col, oL), 5 per thread ----
    const float* xb_base = x + ((size_t)b << 17);
#pragma unroll
    for (int it = 0; it < 5; ++it) {
        const int idx  = wv * 320 + it * 64 + lane;   // 0..2559
        const int col  = idx & 31;
        const int rest = idx >> 5;                    // 0..79
        const int lrow = rest & 3;
        const int oL   = rest >> 2;                   // 0..19
        const int grow = r0 + lrow;
        short8 g;
        if (grow < 32) {
            float v[8];
#pragma unroll
            for (int j = 0; j < 8; ++j) {
                const int m = (oL * 8 + j - 95) & 127;   // channel (L-95) mod 128
                v[j] = xb_base[((m << 5) + grow) * 32 + col];
            }
            union { __hip_bfloat162 h2[4]; short8 s8; } u;
#pragma unroll
            for (int p = 0; p < 4; ++p)
                u.h2[p] = __float22bfloat162_rn(make_float2(v[2 * p], v[2 * p + 1]));
            g = u.s8;
        } else {
            g = short8{0, 0, 0, 0, 0, 0, 0, 0};
        }
        *(short8*)&xs[(lrow * SROWS + col) * LCH + oL * 8] = g;
    }
    // s-apron (col 32,33) zeros: 4 lrow * 2 col * 20 oL = 160 granules
    if (tid < 160) {
        const int oL   = tid % 20;
        const int rem  = tid / 20;       // 0..7
        const int lrow = rem >> 1;
        const int col  = 32 + (rem & 1);
        short8 z = {0, 0, 0, 0, 0, 0, 0, 0};
        *(short8*)&xs[(lrow * SROWS + col) * LCH + oL * 8] = z;
    }

    __syncthreads();

    // ---- A fragments: 9 ds_read_b128 ----
    const int n = lane & 15;      // filter row / D col lane
    const int q = lane >> 4;      // k-octet
    short8 af[9];
#pragma unroll
    for (int t = 0; t < 9; ++t)
        af[t] = *(const short8*)&wf[t * 640 + n * 40 + q * 8];

    // ---- compute: wave -> (row lr, col-half sh), d-group dg ----
    const int tile = wv & 3;
    const int lr   = tile >> 1;
    const int sh   = tile & 1;
    const int s0   = sh << 4;
    const int dg   = wv >> 2;     // 0: even d, 1: odd d

    // lane base (non-negative): col part + 8*(3-q); window imm uses 8*(8 +/- D)
    const char* basep = (const char*)xs +
        ((lr * SROWS + s0 + n) * LCH + 8 * (3 - q)) * 2;
    float* opbase = out + ((size_t)((b * 256 + q * 4) * 32 + (r0 + lr)) << 5) + s0 + n;

    if (dg == 0) {
        compute_d<0, true >(basep, af, opbase);
        compute_d<2, false>(basep, af, opbase);
        compute_d<4, false>(basep, af, opbase);
        compute_d<6, false>(basep, af, opbase);
        compute_d<8, true >(basep, af, opbase);
    } else {
        compute_d<1, false>(basep, af, opbase);
        compute_d<3, false>(basep, af, opbase);
        compute_d<5, false>(basep, af, opbase);
        compute_d<7, false>(basep, af, opbase);
    }
}

extern "C" void kernel_launch(void* const* d_in, const int* in_sizes, int n_in,
                              void* d_out, int out_size, void* d_ws, size_t ws_size,
                              hipStream_t stream) {
    const float* x   = (const float*)d_in[0];   // (16,128,32,32) fp32
    const float* wgt = (const float*)d_in[1];   // (16,32,3,3)   fp32
    float* out = (float*)d_out;                 // (16,256,32,32) fp32
    (void)in_sizes; (void)n_in; (void)out_size; (void)d_ws; (void)ws_size;

    fconv_mfma<<<dim3(16, 16), dim3(NT), 0, stream>>>(x, wgt, out);
}